// Round 1
// baseline (704.816 us; speedup 1.0000x reference)
//
#include <hip/hip_runtime.h>
#include <math.h>

typedef float f32x4 __attribute__((ext_vector_type(4)));
typedef short bf16x8 __attribute__((ext_vector_type(8)));
typedef unsigned short u16;

__device__ __forceinline__ u16 f2bf(float f) {
    union { float f; unsigned u; } v; v.f = f;
    unsigned r = (v.u + 0x7FFFu + ((v.u >> 16) & 1u)) >> 16;
    return (u16)r;
}

__device__ __forceinline__ float splus(float x) {
    // jax.nn.softplus: max(x,0) + log1p(exp(-|x|))
    return fmaxf(x, 0.f) + log1pf(expf(-fabsf(x)));
}

// ---------------------------------------------------------------------------
// setup: build masked bf16 weights (+padded Wo), fused biases, eta->AXE cols
// ---------------------------------------------------------------------------
__global__ __launch_bounds__(256) void setup_w(
    const float* __restrict__ Win, const float* __restrict__ bin,
    const float* __restrict__ Wctx, const float* __restrict__ bctx,
    const float* __restrict__ Wblk, const float* __restrict__ Wout,
    const float* __restrict__ bout, const float* __restrict__ eta,
    u16* __restrict__ W1, float* __restrict__ B1, u16* __restrict__ WB,
    u16* __restrict__ WO, float* __restrict__ BO, u16* __restrict__ AXE)
{
    const long N1 = 8L * 256 * 96;
    const long N2 = 8L * 256;
    const long N3 = 8L * 4 * 256 * 256;
    const long N4 = 8L * 3072 * 256;
    const long N5 = 8L * 3072;
    const long N6 = 8192L * 32;
    const long tot = N1 + N2 + N3 + N4 + N5 + N6;
    for (long i = (long)blockIdx.x * blockDim.x + threadIdx.x; i < tot;
         i += (long)gridDim.x * blockDim.x) {
        long t = i;
        if (t < N1) {
            long l = t / (256 * 96); long r = t % (256 * 96);
            int j = (int)(r / 96), c = (int)(r % 96);
            float v;
            if (c < 64) v = Win[(l * 256 + j) * 64 + c] * (((j % 63) >= c) ? 1.f : 0.f);
            else        v = Wctx[(l * 256 + j) * 32 + (c - 64)];
            W1[i] = f2bf(v);
        } else if ((t -= N1) < N2) {
            B1[t] = bin[t] + bctx[t];
        } else if ((t -= N2) < N3) {
            int rr = (int)((t / 256) % 256);
            int c = (int)(t % 256);
            float v = Wblk[t] * (((rr % 63) >= (c % 63)) ? 1.f : 0.f);
            WB[t] = f2bf(v);
        } else if ((t -= N3) < N4) {
            long l = t / (3072 * 256); long r = t % (3072 * 256);
            int op = (int)(r / 256), j = (int)(r % 256);
            int fd = op / 48, mm = op % 48;
            float v = 0.f;
            if (mm < 47 && fd > (j % 63))
                v = Wout[(l * 3008 + (long)fd * 47 + mm) * 256 + j];
            WO[t] = f2bf(v);
        } else if ((t -= N4) < N5) {
            long l = t / 3072; int op = (int)(t % 3072);
            int fd = op / 48, mm = op % 48;
            BO[t] = (mm < 47) ? bout[l * 3008 + (long)fd * 47 + mm] : 0.f;
        } else {
            t -= N5;
            long b = t / 32; int p = (int)(t % 32);
            AXE[b * 96 + 64 + p] = f2bf(eta[t]);
        }
    }
}

// ---------------------------------------------------------------------------
// data stats: d_mean (65) + d_sq -> DM[0..64], DM[65]
// ---------------------------------------------------------------------------
__global__ __launch_bounds__(128) void dstat(const float* __restrict__ D,
                                             float* __restrict__ DM)
{
    int j = threadIdx.x;
    float s = 0.f, q = 0.f;
    if (j < 65) {
        for (int m = 0; m < 256; ++m) {
            float v = D[m * 65 + j];
            s += v; q += v * v;
        }
        DM[j] = s * (1.f / 256.f);
    }
    __shared__ float red[128];
    red[j] = q; __syncthreads();
    for (int st = 64; st > 0; st >>= 1) {
        if (j < st) red[j] += red[j + st];
        __syncthreads();
    }
    if (j == 0) DM[65] = red[0] * (1.f / 256.f);
}

// ---------------------------------------------------------------------------
// prep per layer: flip x -> XF (f32) + AXE cols 0..63 (bf16); ld reduction
// ---------------------------------------------------------------------------
__global__ __launch_bounds__(256) void prep(
    const float* __restrict__ xin, float* __restrict__ XF, u16* __restrict__ AXE,
    const float* __restrict__ LDPp, float* __restrict__ LDT, int addld)
{
    size_t gt = (size_t)blockIdx.x * 256 + threadIdx.x;
    if (blockIdx.x < 2048) {
        size_t b = gt >> 6; int f = (int)(gt & 63);
        float v = xin[b * 64 + (63 - f)];
        XF[gt] = v;
        AXE[b * 96 + f] = f2bf(v);
    } else {
        int b = (int)(gt - 2048 * 256);
        float s = 0.f;
        if (addld) {
            s = LDT[b];
            for (int g = 0; g < 32; ++g) s += LDPp[(size_t)b * 32 + g];
        }
        LDT[b] = s;
    }
}

// ---------------------------------------------------------------------------
// Generic MFMA GEMM: C(M x 256) = A(M x K, bf16 row-major) * Bw(256 x K)^T
// MODE 0: H=acc+bias;            write H f32, OutB=bf16(relu(H))
// MODE 1: t=relu(acc+bias);      write OutB=bf16(t)
// MODE 2: H=Hin+acc+bias;        write H f32, OutB=bf16(relu(H))
// MODE 3: H=Hin+acc+bias;        write OutB=bf16(H)
// ---------------------------------------------------------------------------
template<int BM, int BN, int MODE>
__global__ __launch_bounds__(256) void gemm_k(
    const u16* __restrict__ A, const u16* __restrict__ Bw,
    const float* __restrict__ bias, const float* __restrict__ Hin,
    float* __restrict__ Hout, u16* __restrict__ OutB, int K)
{
    constexpr int FM = BM / 32;   // frags per wave in M (2x2 wave grid)
    constexpr int FN = BN / 32;
    __shared__ u16 Al[BM * 32];
    __shared__ u16 Bl[BN * 32];
    const int tid = threadIdx.x;
    const int lane = tid & 63, wv = tid >> 6;
    const int wm = wv >> 1, wn = wv & 1;
    const int fr = lane & 15, kg = lane >> 4;
    const int m0 = blockIdx.x * BM, n0 = blockIdx.y * BN;

    const f32x4 vzero = {0.f, 0.f, 0.f, 0.f};
    f32x4 acc[FM][FN];
#pragma unroll
    for (int m = 0; m < FM; ++m)
#pragma unroll
        for (int n = 0; n < FN; ++n) acc[m][n] = vzero;

    for (int kt = 0; kt < K; kt += 32) {
        for (int c = tid * 16; c < BM * 64; c += 4096) {
            int row = c >> 6, kb = (c & 63) >> 1;
            *(int4*)((char*)Al + c) = *(const int4*)(A + (size_t)(m0 + row) * K + kt + kb);
        }
        for (int c = tid * 16; c < BN * 64; c += 4096) {
            int row = c >> 6, kb = (c & 63) >> 1;
            *(int4*)((char*)Bl + c) = *(const int4*)(Bw + (size_t)(n0 + row) * K + kt + kb);
        }
        __syncthreads();
        bf16x8 af[FM], bfv[FN];
#pragma unroll
        for (int m = 0; m < FM; ++m)
            af[m] = *(const bf16x8*)&Al[(wm * FM * 16 + m * 16 + fr) * 32 + kg * 8];
#pragma unroll
        for (int n = 0; n < FN; ++n)
            bfv[n] = *(const bf16x8*)&Bl[(wn * FN * 16 + n * 16 + fr) * 32 + kg * 8];
#pragma unroll
        for (int m = 0; m < FM; ++m)
#pragma unroll
            for (int n = 0; n < FN; ++n)
                acc[m][n] = __builtin_amdgcn_mfma_f32_16x16x32_bf16(af[m], bfv[n], acc[m][n], 0, 0, 0);
        __syncthreads();
    }

#pragma unroll
    for (int m = 0; m < FM; ++m) {
#pragma unroll
        for (int n = 0; n < FN; ++n) {
            int rg = m0 + wm * FM * 16 + m * 16 + kg * 4;
            int cg = n0 + wn * FN * 16 + n * 16 + fr;
            float bs = bias[cg];
#pragma unroll
            for (int j = 0; j < 4; ++j) {
                size_t idx = (size_t)(rg + j) * 256 + cg;
                float v = acc[m][n][j] + bs;
                if constexpr (MODE == 0) {
                    Hout[idx] = v; OutB[idx] = f2bf(fmaxf(v, 0.f));
                } else if constexpr (MODE == 1) {
                    OutB[idx] = f2bf(fmaxf(v, 0.f));
                } else if constexpr (MODE == 2) {
                    float h = Hin[idx] + v; Hout[idx] = h; OutB[idx] = f2bf(fmaxf(h, 0.f));
                } else {
                    float h = Hin[idx] + v; OutB[idx] = f2bf(h);
                }
            }
        }
    }
}

// ---------------------------------------------------------------------------
// Out-GEMM (M x 3072-padded, K=256) with fused RQS spline epilogue.
// Tile 128x96 (2 features/block). Writes Xn (new x) and per-(b,2feat) ld
// partials LDP[b][blockIdx.y].
// ---------------------------------------------------------------------------
__global__ __launch_bounds__(256) void gemm_out_spline(
    const u16* __restrict__ A, const u16* __restrict__ Wo,
    const float* __restrict__ bo, const float* __restrict__ XF,
    float* __restrict__ Xn, float* __restrict__ LDP)
{
    constexpr int BM = 128, BN = 96, FM = 4, FN = 3;
    __shared__ float S[128 * 97];
    u16* Al = (u16*)S;            // 8 KB
    u16* Bl = (u16*)S + 4096;     // 6 KB after Al
    const int tid = threadIdx.x;
    const int lane = tid & 63, wv = tid >> 6;
    const int wm = wv >> 1, wn = wv & 1;
    const int fr = lane & 15, kg = lane >> 4;
    const int m0 = blockIdx.x * BM, n0 = blockIdx.y * BN;

    const f32x4 vzero = {0.f, 0.f, 0.f, 0.f};
    f32x4 acc[FM][FN];
#pragma unroll
    for (int m = 0; m < FM; ++m)
#pragma unroll
        for (int n = 0; n < FN; ++n) acc[m][n] = vzero;

    for (int kt = 0; kt < 256; kt += 32) {
        for (int c = tid * 16; c < BM * 64; c += 4096) {
            int row = c >> 6, kb = (c & 63) >> 1;
            *(int4*)((char*)Al + c) = *(const int4*)(A + (size_t)(m0 + row) * 256 + kt + kb);
        }
        for (int c = tid * 16; c < BN * 64; c += 4096) {
            int row = c >> 6, kb = (c & 63) >> 1;
            *(int4*)((char*)Bl + c) = *(const int4*)(Wo + (size_t)(n0 + row) * 256 + kt + kb);
        }
        __syncthreads();
        bf16x8 af[FM], bfv[FN];
#pragma unroll
        for (int m = 0; m < FM; ++m)
            af[m] = *(const bf16x8*)&Al[(wm * 64 + m * 16 + fr) * 32 + kg * 8];
#pragma unroll
        for (int n = 0; n < FN; ++n)
            bfv[n] = *(const bf16x8*)&Bl[(wn * 48 + n * 16 + fr) * 32 + kg * 8];
#pragma unroll
        for (int m = 0; m < FM; ++m)
#pragma unroll
            for (int n = 0; n < FN; ++n)
                acc[m][n] = __builtin_amdgcn_mfma_f32_16x16x32_bf16(af[m], bfv[n], acc[m][n], 0, 0, 0);
        __syncthreads();
    }

    // dump acc (+bias) into S with pitch 97 (bank-friendly for the spline read)
#pragma unroll
    for (int m = 0; m < FM; ++m)
#pragma unroll
        for (int n = 0; n < FN; ++n) {
            int cl = wn * 48 + n * 16 + fr;
            float bs = bo[n0 + cl];
#pragma unroll
            for (int j = 0; j < 4; ++j) {
                int rl = wm * 64 + m * 16 + kg * 4 + j;
                S[rl * 97 + cl] = acc[m][n][j] + bs;
            }
        }
    __syncthreads();

    // ---- RQS spline: one thread per (row, feature) pair; 256 = 128 x 2 ----
    const int r = tid >> 1, fi = tid & 1;
    const int b = m0 + r;
    const int fg = blockIdx.y * 2 + fi;
    const float* o_ = &S[r * 97 + fi * 48];

    float xin = XF[(size_t)b * 64 + fg];
    bool inside = (xin >= -10.f) && (xin <= 10.f);
    float xs = fminf(fmaxf(xin, -10.f), 10.f);

    float cwv[17], chv[17];
    {
        float e[16]; float mx = -1e30f;
#pragma unroll
        for (int i = 0; i < 16; ++i) { float u = o_[i] * 0.0625f; e[i] = u; mx = fmaxf(mx, u); }
        float s = 0.f;
#pragma unroll
        for (int i = 0; i < 16; ++i) { e[i] = expf(e[i] - mx); s += e[i]; }
        float inv = (1.f - 16.f * 1e-8f) / s;
        float cum = 0.f; cwv[0] = -10.f;
#pragma unroll
        for (int i = 0; i < 15; ++i) { cum += 1e-8f + inv * e[i]; cwv[i + 1] = 20.f * cum - 10.f; }
        cwv[16] = 10.f;
    }
    {
        float e[16]; float mx = -1e30f;
#pragma unroll
        for (int i = 0; i < 16; ++i) { float u = o_[16 + i] * 0.0625f; e[i] = u; mx = fmaxf(mx, u); }
        float s = 0.f;
#pragma unroll
        for (int i = 0; i < 16; ++i) { e[i] = expf(e[i] - mx); s += e[i]; }
        float inv = (1.f - 16.f * 1e-8f) / s;
        float cum = 0.f; chv[0] = -10.f;
#pragma unroll
        for (int i = 0; i < 15; ++i) { cum += 1e-8f + inv * e[i]; chv[i + 1] = 20.f * cum - 10.f; }
        chv[16] = 10.f;
    }

    int idx = 0;
#pragma unroll
    for (int k = 1; k < 16; ++k) if (xs >= cwv[k]) idx = k;

    // select bin quantities without dynamic register indexing
    float icw = cwv[0], cwn = cwv[1], ich = chv[0], chn = chv[1];
    float udl = 0.f, udr = o_[32];
#pragma unroll
    for (int k = 1; k < 16; ++k) {
        if (idx == k) {
            icw = cwv[k]; cwn = cwv[k + 1]; ich = chv[k]; chn = chv[k + 1];
            udl = o_[32 + k - 1]; udr = (k < 15) ? o_[32 + k] : 0.f;
        }
    }
    float d0 = (idx == 0)  ? 1.f : 1e-8f + splus(udl);
    float d1 = (idx == 15) ? 1.f : 1e-8f + splus(udr);
    float iw = cwn - icw, ih = chn - ich;
    float delta = ih / iw;
    float t = (xs - icw) / iw;
    float tt = t * (1.f - t);
    float denom = delta + (d0 + d1 - 2.f * delta) * tt;
    float y = ich + ih * (delta * t * t + d0 * tt) / denom;
    float omt = 1.f - t;
    float dnum = delta * delta * (d1 * t * t + 2.f * delta * tt + d0 * omt * omt);
    float ldv = logf(dnum) - 2.f * logf(denom);
    if (!inside) { y = xin; ldv = 0.f; }

    Xn[(size_t)b * 64 + fg] = y;
    float other = __shfl_xor(ldv, 1);
    if (fi == 0) LDP[(size_t)b * 32 + blockIdx.y] = ldv + other;
}

// ---------------------------------------------------------------------------
// finals: stick-breaking + per-sample objective, then reduction
// ---------------------------------------------------------------------------
__global__ __launch_bounds__(256) void final1(
    const float* __restrict__ X, const float* __restrict__ z,
    const float* __restrict__ LDT, const float* __restrict__ LDP,
    const float* __restrict__ DM, float* __restrict__ PART)
{
    int tid = threadIdx.x;
    int b = blockIdx.x * 256 + tid;
    float ldt = LDT[b];
    for (int g = 0; g < 32; ++g) ldt += LDP[(size_t)b * 32 + g];
    float pre = 0.f, lvs = 0.f, wls = 0.f, lp = 0.f, tdm = 0.f, tsq = 0.f;
    for (int i = 0; i < 64; ++i) {
        float xi = X[(size_t)b * 64 + i];
        float lv = -splus(-xi), l1 = -splus(xi);
        float lt = lv + pre;           // log_theta[i] (exclusive prefix)
        float th = expf(lt);
        lp += logf(fmaxf(th, 1e-10f));
        tdm += th * DM[i]; tsq += th * th;
        lvs += lv; wls += (float)(64 - i) * l1;
        pre += l1;
    }
    float th = expf(pre);              // log_theta[64] = sum(log_1v)
    lp += logf(fmaxf(th, 1e-10f)); tdm += th * DM[64]; tsq += th * th;
    float zs = 0.f;
    for (int i = 0; i < 64; ++i) { float zz = z[(size_t)b * 64 + i]; zs += zz * zz; }
    float logqz = -0.5f * zs - 58.812066f;      // 0.5*64*ln(2*pi)
    float log_q = logqz - (ldt + lvs + wls);
    float log_lik = -0.5f * (DM[65] - 2.f * tdm + tsq);
    float val = log_q - lp - log_lik;

    __shared__ float red[256];
    red[tid] = val; __syncthreads();
    for (int s = 128; s > 0; s >>= 1) {
        if (tid < s) red[tid] += red[tid + s];
        __syncthreads();
    }
    if (tid == 0) PART[blockIdx.x] = red[0];
}

__global__ __launch_bounds__(64) void final2(const float* __restrict__ PART,
                                             float* __restrict__ out)
{
    int tid = threadIdx.x;
    float s = (tid < 32) ? PART[tid] : 0.f;
    for (int o = 16; o > 0; o >>= 1) s += __shfl_down(s, o);
    if (tid == 0) out[0] = s * (1.f / 8192.f);
}

// ---------------------------------------------------------------------------
extern "C" void kernel_launch(void* const* d_in, const int* in_sizes, int n_in,
                              void* d_out, int out_size, void* d_ws, size_t ws_size,
                              hipStream_t stream)
{
    (void)in_sizes; (void)n_in; (void)out_size; (void)ws_size;
    const float* z    = (const float*)d_in[0];
    const float* eta  = (const float*)d_in[1];
    const float* dat  = (const float*)d_in[2];
    const float* Win  = (const float*)d_in[3];
    const float* bin  = (const float*)d_in[4];
    const float* Wctx = (const float*)d_in[5];
    const float* bctx = (const float*)d_in[6];
    const float* Wblk = (const float*)d_in[7];
    const float* bblk = (const float*)d_in[8];
    const float* Wout = (const float*)d_in[9];
    const float* bout = (const float*)d_in[10];
    float* out = (float*)d_out;

    char* w = (char*)d_ws;
    size_t off = 0;
    auto alloc = [&](size_t bytes) {
        void* p = w + off;
        off += (bytes + 255) & ~(size_t)255;
        return p;
    };
    u16*   W1  = (u16*)  alloc(8L * 256 * 96 * 2);
    float* B1  = (float*)alloc(8L * 256 * 4);
    u16*   WB  = (u16*)  alloc(8L * 4 * 256 * 256 * 2);
    u16*   WO  = (u16*)  alloc(8L * 3072 * 256 * 2);
    float* BO  = (float*)alloc(8L * 3072 * 4);
    u16*   AXE = (u16*)  alloc(8192L * 96 * 2);
    float* XF  = (float*)alloc(8192L * 64 * 4);
    float* XC  = (float*)alloc(8192L * 64 * 4);
    float* H   = (float*)alloc(8192L * 256 * 4);
    u16*   HB  = (u16*)  alloc(8192L * 256 * 2);
    u16*   TB  = (u16*)  alloc(8192L * 256 * 2);
    float* LDP = (float*)alloc(8192L * 32 * 4);
    float* LDT = (float*)alloc(8192L * 4);
    float* DM  = (float*)alloc(66 * 4);
    float* PART= (float*)alloc(64 * 4);

    setup_w<<<dim3(2048), dim3(256), 0, stream>>>(
        Win, bin, Wctx, bctx, Wblk, Wout, bout, eta, W1, B1, WB, WO, BO, AXE);
    dstat<<<dim3(1), dim3(128), 0, stream>>>(dat, DM);

    for (int l = 0; l < 8; ++l) {
        prep<<<dim3(2080), dim3(256), 0, stream>>>(
            (l == 0) ? z : (const float*)XC, XF, AXE, LDP, LDT, (l > 0) ? 1 : 0);
        gemm_k<64, 64, 0><<<dim3(128, 4), dim3(256), 0, stream>>>(
            AXE, W1 + (size_t)l * 256 * 96, B1 + l * 256,
            (const float*)nullptr, H, HB, 96);
        gemm_k<64, 64, 1><<<dim3(128, 4), dim3(256), 0, stream>>>(
            HB, WB + ((size_t)l * 4 + 0) * 65536, bblk + (l * 4 + 0) * 256,
            (const float*)nullptr, (float*)nullptr, TB, 256);
        gemm_k<64, 64, 2><<<dim3(128, 4), dim3(256), 0, stream>>>(
            TB, WB + ((size_t)l * 4 + 1) * 65536, bblk + (l * 4 + 1) * 256,
            H, H, HB, 256);
        gemm_k<64, 64, 1><<<dim3(128, 4), dim3(256), 0, stream>>>(
            HB, WB + ((size_t)l * 4 + 2) * 65536, bblk + (l * 4 + 2) * 256,
            (const float*)nullptr, (float*)nullptr, TB, 256);
        gemm_k<64, 64, 3><<<dim3(128, 4), dim3(256), 0, stream>>>(
            TB, WB + ((size_t)l * 4 + 3) * 65536, bblk + (l * 4 + 3) * 256,
            H, (float*)nullptr, HB, 256);
        gemm_out_spline<<<dim3(64, 32), dim3(256), 0, stream>>>(
            HB, WO + (size_t)l * 3072 * 256, BO + l * 3072, XF, XC, LDP);
    }
    final1<<<dim3(32), dim3(256), 0, stream>>>(XC, z, LDT, LDP, DM, PART);
    final2<<<dim3(1), dim3(64), 0, stream>>>(PART, out);
}

// Round 2
// 704.295 us; speedup vs baseline: 1.0007x; 1.0007x over previous
//
#include <hip/hip_runtime.h>
#include <math.h>

typedef float f32x4 __attribute__((ext_vector_type(4)));
typedef short bf16x8 __attribute__((ext_vector_type(8)));
typedef unsigned short u16;

__device__ __forceinline__ u16 f2bf(float f) {
    union { float f; unsigned u; } v; v.f = f;
    unsigned r = (v.u + 0x7FFFu + ((v.u >> 16) & 1u)) >> 16;
    return (u16)r;
}
__device__ __forceinline__ float bf2f(u16 h) {
    union { unsigned u; float f; } v; v.u = ((unsigned)h) << 16;
    return v.f;
}
__device__ __forceinline__ float splus(float x) {
    return fmaxf(x, 0.f) + log1pf(expf(-fabsf(x)));
}

// ---------------------------------------------------------------------------
// setup: build masked bf16 weights (+padded Wo), fused biases, eta->AXE cols
// ---------------------------------------------------------------------------
__global__ __launch_bounds__(256) void setup_w(
    const float* __restrict__ Win, const float* __restrict__ bin,
    const float* __restrict__ Wctx, const float* __restrict__ bctx,
    const float* __restrict__ Wblk, const float* __restrict__ Wout,
    const float* __restrict__ bout, const float* __restrict__ eta,
    u16* __restrict__ W1, float* __restrict__ B1, u16* __restrict__ WB,
    u16* __restrict__ WO, float* __restrict__ BO, u16* __restrict__ AXE)
{
    const long N1 = 8L * 256 * 96;
    const long N2 = 8L * 256;
    const long N3 = 8L * 4 * 256 * 256;
    const long N4 = 8L * 3072 * 256;
    const long N5 = 8L * 3072;
    const long N6 = 8192L * 32;
    const long tot = N1 + N2 + N3 + N4 + N5 + N6;
    for (long i = (long)blockIdx.x * blockDim.x + threadIdx.x; i < tot;
         i += (long)gridDim.x * blockDim.x) {
        long t = i;
        if (t < N1) {
            long l = t / (256 * 96); long r = t % (256 * 96);
            int j = (int)(r / 96), c = (int)(r % 96);
            float v;
            if (c < 64) v = Win[(l * 256 + j) * 64 + c] * (((j % 63) >= c) ? 1.f : 0.f);
            else        v = Wctx[(l * 256 + j) * 32 + (c - 64)];
            W1[i] = f2bf(v);
        } else if ((t -= N1) < N2) {
            B1[t] = bin[t] + bctx[t];
        } else if ((t -= N2) < N3) {
            int rr = (int)((t / 256) % 256);
            int c = (int)(t % 256);
            float v = Wblk[t] * (((rr % 63) >= (c % 63)) ? 1.f : 0.f);
            WB[t] = f2bf(v);
        } else if ((t -= N3) < N4) {
            long l = t / (3072 * 256); long r = t % (3072 * 256);
            int op = (int)(r / 256), j = (int)(r % 256);
            int fd = op / 48, mm = op % 48;
            float v = 0.f;
            if (mm < 47 && fd > (j % 63))
                v = Wout[(l * 3008 + (long)fd * 47 + mm) * 256 + j];
            WO[t] = f2bf(v);
        } else if ((t -= N4) < N5) {
            long l = t / 3072; int op = (int)(t % 3072);
            int fd = op / 48, mm = op % 48;
            BO[t] = (mm < 47) ? bout[l * 3008 + (long)fd * 47 + mm] : 0.f;
        } else {
            t -= N5;
            long b = t / 32; int p = (int)(t % 32);
            AXE[b * 96 + 64 + p] = f2bf(eta[t]);
        }
    }
}

// ---------------------------------------------------------------------------
// data stats: d_mean (65) + d_sq -> DM[0..64], DM[65]
// ---------------------------------------------------------------------------
__global__ __launch_bounds__(128) void dstat(const float* __restrict__ D,
                                             float* __restrict__ DM)
{
    int j = threadIdx.x;
    float s = 0.f, q = 0.f;
    if (j < 65) {
        for (int m = 0; m < 256; ++m) {
            float v = D[m * 65 + j];
            s += v; q += v * v;
        }
        DM[j] = s * (1.f / 256.f);
    }
    __shared__ float red[128];
    red[j] = q; __syncthreads();
    for (int st = 64; st > 0; st >>= 1) {
        if (j < st) red[j] += red[j + st];
        __syncthreads();
    }
    if (j == 0) DM[65] = red[0] * (1.f / 256.f);
}

// ---------------------------------------------------------------------------
// prep0: flip z -> XF (f32) + AXE cols 0..63 (bf16)
// ---------------------------------------------------------------------------
__global__ __launch_bounds__(256) void prep0(
    const float* __restrict__ z, float* __restrict__ XF, u16* __restrict__ AXE)
{
    size_t gt = (size_t)blockIdx.x * 256 + threadIdx.x;
    size_t b = gt >> 6; int f = (int)(gt & 63);
    float v = z[b * 64 + (63 - f)];
    XF[gt] = v;
    AXE[b * 96 + f] = f2bf(v);
}

// ---------------------------------------------------------------------------
// Generic MFMA GEMM: C(M x 256) = A(M x K, bf16 row-major) * Bw(256 x K)^T
// LDS rows padded to 40 u16 (80B) -> <=2-way bank aliasing (free).
// MODE 0: H=acc+bias;            write H f32, OutB=bf16(relu(H))
// MODE 1: t=relu(acc+bias);      write OutB=bf16(t)
// MODE 2: H=Hin+acc+bias;        write H f32, OutB=bf16(relu(H))
// MODE 3: H=Hin+acc+bias;        write OutB=bf16(H)
// ---------------------------------------------------------------------------
template<int BM, int BN, int MODE>
__global__ __launch_bounds__(256) void gemm_k(
    const u16* __restrict__ A, const u16* __restrict__ Bw,
    const float* __restrict__ bias, const float* __restrict__ Hin,
    float* __restrict__ Hout, u16* __restrict__ OutB, int K)
{
    constexpr int FM = BM / 32;   // frags per wave in M (2x2 wave grid)
    constexpr int FN = BN / 32;
    __shared__ u16 Al[BM * 40];
    __shared__ u16 Bl[BN * 40];
    const int tid = threadIdx.x;
    const int lane = tid & 63, wv = tid >> 6;
    const int wm = wv >> 1, wn = wv & 1;
    const int fr = lane & 15, kg = lane >> 4;
    const int m0 = blockIdx.x * BM, n0 = blockIdx.y * BN;

    const f32x4 vzero = {0.f, 0.f, 0.f, 0.f};
    f32x4 acc[FM][FN];
#pragma unroll
    for (int m = 0; m < FM; ++m)
#pragma unroll
        for (int n = 0; n < FN; ++n) acc[m][n] = vzero;

    for (int kt = 0; kt < K; kt += 32) {
        for (int c = tid * 16; c < BM * 64; c += 4096) {
            int row = c >> 6, kb = (c & 63) >> 1;
            *(int4*)&Al[row * 40 + kb] = *(const int4*)(A + (size_t)(m0 + row) * K + kt + kb);
        }
        for (int c = tid * 16; c < BN * 64; c += 4096) {
            int row = c >> 6, kb = (c & 63) >> 1;
            *(int4*)&Bl[row * 40 + kb] = *(const int4*)(Bw + (size_t)(n0 + row) * K + kt + kb);
        }
        __syncthreads();
        bf16x8 af[FM], bfv[FN];
#pragma unroll
        for (int m = 0; m < FM; ++m)
            af[m] = *(const bf16x8*)&Al[(wm * FM * 16 + m * 16 + fr) * 40 + kg * 8];
#pragma unroll
        for (int n = 0; n < FN; ++n)
            bfv[n] = *(const bf16x8*)&Bl[(wn * FN * 16 + n * 16 + fr) * 40 + kg * 8];
#pragma unroll
        for (int m = 0; m < FM; ++m)
#pragma unroll
            for (int n = 0; n < FN; ++n)
                acc[m][n] = __builtin_amdgcn_mfma_f32_16x16x32_bf16(af[m], bfv[n], acc[m][n], 0, 0, 0);
        __syncthreads();
    }

#pragma unroll
    for (int m = 0; m < FM; ++m) {
#pragma unroll
        for (int n = 0; n < FN; ++n) {
            int rg = m0 + wm * FM * 16 + m * 16 + kg * 4;
            int cg = n0 + wn * FN * 16 + n * 16 + fr;
            float bs = bias[cg];
#pragma unroll
            for (int j = 0; j < 4; ++j) {
                size_t idx = (size_t)(rg + j) * 256 + cg;
                float v = acc[m][n][j] + bs;
                if constexpr (MODE == 0) {
                    Hout[idx] = v; OutB[idx] = f2bf(fmaxf(v, 0.f));
                } else if constexpr (MODE == 1) {
                    OutB[idx] = f2bf(fmaxf(v, 0.f));
                } else if constexpr (MODE == 2) {
                    float h = Hin[idx] + v; Hout[idx] = h; OutB[idx] = f2bf(fmaxf(h, 0.f));
                } else {
                    float h = Hin[idx] + v; OutB[idx] = f2bf(h);
                }
            }
        }
    }
}

// ---------------------------------------------------------------------------
// Out-GEMM (M x 3072-padded, K=256) with fused RQS spline epilogue.
// Tile 128x96 (2 features/block). bf16 LDS staging (pitch 98) for the
// spline inputs -> 25 KB LDS -> 6 blocks/CU. Writes Xn, next-layer XF/AXE
// (flipped), and accumulates ld partials into LDP[b][blockIdx.y].
// ---------------------------------------------------------------------------
__global__ __launch_bounds__(256) void gemm_out_spline(
    const u16* __restrict__ A, const u16* __restrict__ Wo,
    const float* __restrict__ bo, const float* __restrict__ XF,
    float* __restrict__ Xn, float* __restrict__ XFnext, u16* __restrict__ AXE,
    float* __restrict__ LDP, int first)
{
    constexpr int FM = 4, FN = 3;
    __shared__ u16 SMEM[128 * 98];       // 25088 B
    u16* Al = SMEM;                      // 128*40 = 5120 u16
    u16* Bl = SMEM + 5120;               //  96*40 = 3840 u16
    const int tid = threadIdx.x;
    const int lane = tid & 63, wv = tid >> 6;
    const int wm = wv >> 1, wn = wv & 1;
    const int fr = lane & 15, kg = lane >> 4;
    const int m0 = blockIdx.x * 128, n0 = blockIdx.y * 96;

    const f32x4 vzero = {0.f, 0.f, 0.f, 0.f};
    f32x4 acc[FM][FN];
#pragma unroll
    for (int m = 0; m < FM; ++m)
#pragma unroll
        for (int n = 0; n < FN; ++n) acc[m][n] = vzero;

    for (int kt = 0; kt < 256; kt += 32) {
        for (int c = tid * 16; c < 128 * 64; c += 4096) {
            int row = c >> 6, kb = (c & 63) >> 1;
            *(int4*)&Al[row * 40 + kb] = *(const int4*)(A + (size_t)(m0 + row) * 256 + kt + kb);
        }
        for (int c = tid * 16; c < 96 * 64; c += 4096) {
            int row = c >> 6, kb = (c & 63) >> 1;
            *(int4*)&Bl[row * 40 + kb] = *(const int4*)(Wo + (size_t)(n0 + row) * 256 + kt + kb);
        }
        __syncthreads();
        bf16x8 af[FM], bfv[FN];
#pragma unroll
        for (int m = 0; m < FM; ++m)
            af[m] = *(const bf16x8*)&Al[(wm * 64 + m * 16 + fr) * 40 + kg * 8];
#pragma unroll
        for (int n = 0; n < FN; ++n)
            bfv[n] = *(const bf16x8*)&Bl[(wn * 48 + n * 16 + fr) * 40 + kg * 8];
#pragma unroll
        for (int m = 0; m < FM; ++m)
#pragma unroll
            for (int n = 0; n < FN; ++n)
                acc[m][n] = __builtin_amdgcn_mfma_f32_16x16x32_bf16(af[m], bfv[n], acc[m][n], 0, 0, 0);
        __syncthreads();
    }

    // dump acc (+bias) into SMEM as bf16, pitch 98
#pragma unroll
    for (int m = 0; m < FM; ++m)
#pragma unroll
        for (int n = 0; n < FN; ++n) {
            int cl = wn * 48 + n * 16 + fr;
            float bs = bo[n0 + cl];
#pragma unroll
            for (int j = 0; j < 4; ++j) {
                int rl = wm * 64 + m * 16 + kg * 4 + j;
                SMEM[rl * 98 + cl] = f2bf(acc[m][n][j] + bs);
            }
        }
    __syncthreads();

    // ---- RQS spline: one thread per (row, feature) pair; 256 = 128 x 2 ----
    const int r = tid >> 1, fi = tid & 1;
    const int b = m0 + r;
    const int fg = blockIdx.y * 2 + fi;
    const u16* o_ = &SMEM[r * 98 + fi * 48];

    float xin = XF[(size_t)b * 64 + fg];
    bool inside = (xin >= -10.f) && (xin <= 10.f);
    float xs = fminf(fmaxf(xin, -10.f), 10.f);

    float cwv[17], chv[17];
    {
        float e[16]; float mx = -1e30f;
#pragma unroll
        for (int i = 0; i < 16; ++i) { float u = bf2f(o_[i]) * 0.0625f; e[i] = u; mx = fmaxf(mx, u); }
        float s = 0.f;
#pragma unroll
        for (int i = 0; i < 16; ++i) { e[i] = expf(e[i] - mx); s += e[i]; }
        float inv = (1.f - 16.f * 1e-8f) / s;
        float cum = 0.f; cwv[0] = -10.f;
#pragma unroll
        for (int i = 0; i < 15; ++i) { cum += 1e-8f + inv * e[i]; cwv[i + 1] = 20.f * cum - 10.f; }
        cwv[16] = 10.f;
    }
    {
        float e[16]; float mx = -1e30f;
#pragma unroll
        for (int i = 0; i < 16; ++i) { float u = bf2f(o_[16 + i]) * 0.0625f; e[i] = u; mx = fmaxf(mx, u); }
        float s = 0.f;
#pragma unroll
        for (int i = 0; i < 16; ++i) { e[i] = expf(e[i] - mx); s += e[i]; }
        float inv = (1.f - 16.f * 1e-8f) / s;
        float cum = 0.f; chv[0] = -10.f;
#pragma unroll
        for (int i = 0; i < 15; ++i) { cum += 1e-8f + inv * e[i]; chv[i + 1] = 20.f * cum - 10.f; }
        chv[16] = 10.f;
    }

    int idx = 0;
#pragma unroll
    for (int k = 1; k < 16; ++k) if (xs >= cwv[k]) idx = k;

    float icw = cwv[0], cwn = cwv[1], ich = chv[0], chn = chv[1];
    float udl = 0.f, udr = bf2f(o_[32]);
#pragma unroll
    for (int k = 1; k < 16; ++k) {
        if (idx == k) {
            icw = cwv[k]; cwn = cwv[k + 1]; ich = chv[k]; chn = chv[k + 1];
            udl = bf2f(o_[32 + k - 1]); udr = (k < 15) ? bf2f(o_[32 + k]) : 0.f;
        }
    }
    float d0 = (idx == 0)  ? 1.f : 1e-8f + splus(udl);
    float d1 = (idx == 15) ? 1.f : 1e-8f + splus(udr);
    float iw = cwn - icw, ih = chn - ich;
    float delta = ih / iw;
    float t = (xs - icw) / iw;
    float tt = t * (1.f - t);
    float denom = delta + (d0 + d1 - 2.f * delta) * tt;
    float y = ich + ih * (delta * t * t + d0 * tt) / denom;
    float omt = 1.f - t;
    float dnum = delta * delta * (d1 * t * t + 2.f * delta * tt + d0 * omt * omt);
    float ldv = logf(dnum) - 2.f * logf(denom);
    if (!inside) { y = xin; ldv = 0.f; }

    Xn[(size_t)b * 64 + fg] = y;
    // next layer's flipped inputs
    XFnext[(size_t)b * 64 + (63 - fg)] = y;
    AXE[(size_t)b * 96 + (63 - fg)] = f2bf(y);

    float other = __shfl_xor(ldv, 1);
    if (fi == 0) {
        size_t o = (size_t)b * 32 + blockIdx.y;
        float v = ldv + other;
        LDP[o] = first ? v : (LDP[o] + v);
    }
}

// ---------------------------------------------------------------------------
// finals: stick-breaking + per-sample objective, then reduction
// ---------------------------------------------------------------------------
__global__ __launch_bounds__(256) void final1(
    const float* __restrict__ X, const float* __restrict__ z,
    const float* __restrict__ LDP, const float* __restrict__ DM,
    float* __restrict__ PART)
{
    int tid = threadIdx.x;
    int b = blockIdx.x * 256 + tid;
    float ldt = 0.f;
    for (int g = 0; g < 32; ++g) ldt += LDP[(size_t)b * 32 + g];
    float pre = 0.f, lvs = 0.f, wls = 0.f, lp = 0.f, tdm = 0.f, tsq = 0.f;
    for (int i = 0; i < 64; ++i) {
        float xi = X[(size_t)b * 64 + i];
        float lv = -splus(-xi), l1 = -splus(xi);
        float lt = lv + pre;
        float th = expf(lt);
        lp += logf(fmaxf(th, 1e-10f));
        tdm += th * DM[i]; tsq += th * th;
        lvs += lv; wls += (float)(64 - i) * l1;
        pre += l1;
    }
    float th = expf(pre);
    lp += logf(fmaxf(th, 1e-10f)); tdm += th * DM[64]; tsq += th * th;
    float zs = 0.f;
    for (int i = 0; i < 64; ++i) { float zz = z[(size_t)b * 64 + i]; zs += zz * zz; }
    float logqz = -0.5f * zs - 58.812066f;
    float log_q = logqz - (ldt + lvs + wls);
    float log_lik = -0.5f * (DM[65] - 2.f * tdm + tsq);
    float val = log_q - lp - log_lik;

    __shared__ float red[256];
    red[tid] = val; __syncthreads();
    for (int s = 128; s > 0; s >>= 1) {
        if (tid < s) red[tid] += red[tid + s];
        __syncthreads();
    }
    if (tid == 0) PART[blockIdx.x] = red[0];
}

__global__ __launch_bounds__(64) void final2(const float* __restrict__ PART,
                                             float* __restrict__ out)
{
    int tid = threadIdx.x;
    float s = (tid < 32) ? PART[tid] : 0.f;
    for (int o = 16; o > 0; o >>= 1) s += __shfl_down(s, o);
    if (tid == 0) out[0] = s * (1.f / 8192.f);
}

// ---------------------------------------------------------------------------
extern "C" void kernel_launch(void* const* d_in, const int* in_sizes, int n_in,
                              void* d_out, int out_size, void* d_ws, size_t ws_size,
                              hipStream_t stream)
{
    (void)in_sizes; (void)n_in; (void)out_size; (void)ws_size;
    const float* z    = (const float*)d_in[0];
    const float* eta  = (const float*)d_in[1];
    const float* dat  = (const float*)d_in[2];
    const float* Win  = (const float*)d_in[3];
    const float* bin  = (const float*)d_in[4];
    const float* Wctx = (const float*)d_in[5];
    const float* bctx = (const float*)d_in[6];
    const float* Wblk = (const float*)d_in[7];
    const float* bblk = (const float*)d_in[8];
    const float* Wout = (const float*)d_in[9];
    const float* bout = (const float*)d_in[10];
    float* out = (float*)d_out;

    char* w = (char*)d_ws;
    size_t off = 0;
    auto alloc = [&](size_t bytes) {
        void* p = w + off;
        off += (bytes + 255) & ~(size_t)255;
        return p;
    };
    u16*   W1  = (u16*)  alloc(8L * 256 * 96 * 2);
    float* B1  = (float*)alloc(8L * 256 * 4);
    u16*   WB  = (u16*)  alloc(8L * 4 * 256 * 256 * 2);
    u16*   WO  = (u16*)  alloc(8L * 3072 * 256 * 2);
    float* BO  = (float*)alloc(8L * 3072 * 4);
    u16*   AXE = (u16*)  alloc(8192L * 96 * 2);
    float* XFa = (float*)alloc(8192L * 64 * 4);
    float* XFb = (float*)alloc(8192L * 64 * 4);
    float* XC  = (float*)alloc(8192L * 64 * 4);
    float* H   = (float*)alloc(8192L * 256 * 4);
    u16*   HB  = (u16*)  alloc(8192L * 256 * 2);
    u16*   TB  = (u16*)  alloc(8192L * 256 * 2);
    float* LDP = (float*)alloc(8192L * 32 * 4);
    float* DM  = (float*)alloc(66 * 4);
    float* PART= (float*)alloc(64 * 4);

    setup_w<<<dim3(2048), dim3(256), 0, stream>>>(
        Win, bin, Wctx, bctx, Wblk, Wout, bout, eta, W1, B1, WB, WO, BO, AXE);
    dstat<<<dim3(1), dim3(128), 0, stream>>>(dat, DM);
    prep0<<<dim3(2048), dim3(256), 0, stream>>>(z, XFa, AXE);

    for (int l = 0; l < 8; ++l) {
        float* XFin  = (l & 1) ? XFb : XFa;
        float* XFout = (l & 1) ? XFa : XFb;
        gemm_k<64, 64, 0><<<dim3(128, 4), dim3(256), 0, stream>>>(
            AXE, W1 + (size_t)l * 256 * 96, B1 + l * 256,
            (const float*)nullptr, H, HB, 96);
        gemm_k<64, 64, 1><<<dim3(128, 4), dim3(256), 0, stream>>>(
            HB, WB + ((size_t)l * 4 + 0) * 65536, bblk + (l * 4 + 0) * 256,
            (const float*)nullptr, (float*)nullptr, TB, 256);
        gemm_k<64, 64, 2><<<dim3(128, 4), dim3(256), 0, stream>>>(
            TB, WB + ((size_t)l * 4 + 1) * 65536, bblk + (l * 4 + 1) * 256,
            H, H, HB, 256);
        gemm_k<64, 64, 1><<<dim3(128, 4), dim3(256), 0, stream>>>(
            HB, WB + ((size_t)l * 4 + 2) * 65536, bblk + (l * 4 + 2) * 256,
            (const float*)nullptr, (float*)nullptr, TB, 256);
        gemm_k<64, 64, 3><<<dim3(128, 4), dim3(256), 0, stream>>>(
            TB, WB + ((size_t)l * 4 + 3) * 65536, bblk + (l * 4 + 3) * 256,
            H, (float*)nullptr, HB, 256);
        gemm_out_spline<<<dim3(64, 32), dim3(256), 0, stream>>>(
            HB, WO + (size_t)l * 3072 * 256, BO + l * 3072, XFin,
            XC, XFout, AXE, LDP, (l == 0) ? 1 : 0);
    }
    final1<<<dim3(32), dim3(256), 0, stream>>>(XC, z, LDP, DM, PART);
    final2<<<dim3(1), dim3(64), 0, stream>>>(PART, out);
}

// Round 3
// 502.200 us; speedup vs baseline: 1.4035x; 1.4024x over previous
//
#include <hip/hip_runtime.h>
#include <math.h>

typedef float f32x4 __attribute__((ext_vector_type(4)));
typedef short bf16x8 __attribute__((ext_vector_type(8)));
typedef unsigned short u16;

__device__ __forceinline__ u16 f2bf(float f) {
    union { float f; unsigned u; } v; v.f = f;
    return (u16)((v.u + 0x7FFFu + ((v.u >> 16) & 1u)) >> 16);
}
__device__ __forceinline__ float bf2f(u16 h) {
    union { unsigned u; float f; } v; v.u = ((unsigned)h) << 16;
    return v.f;
}
// fast softplus: max(x,0) + log(1+exp(-|x|)) with native exp/log (tol is 2%)
__device__ __forceinline__ float splusf(float x) {
    return fmaxf(x, 0.f) + __logf(1.f + __expf(-fabsf(x)));
}

// ---------------------------------------------------------------------------
// setup: build masked bf16 weights (+padded Wo), fused biases, eta->AXE cols
// ---------------------------------------------------------------------------
__global__ __launch_bounds__(256) void setup_w(
    const float* __restrict__ Win, const float* __restrict__ bin,
    const float* __restrict__ Wctx, const float* __restrict__ bctx,
    const float* __restrict__ Wblk, const float* __restrict__ Wout,
    const float* __restrict__ bout, const float* __restrict__ eta,
    u16* __restrict__ W1, float* __restrict__ B1, u16* __restrict__ WB,
    u16* __restrict__ WO, float* __restrict__ BO, u16* __restrict__ AXE)
{
    const long N1 = 8L * 256 * 96;
    const long N2 = 8L * 256;
    const long N3 = 8L * 4 * 256 * 256;
    const long N4 = 8L * 3072 * 256;
    const long N5 = 8L * 3072;
    const long N6 = 8192L * 32;
    const long tot = N1 + N2 + N3 + N4 + N5 + N6;
    for (long i = (long)blockIdx.x * blockDim.x + threadIdx.x; i < tot;
         i += (long)gridDim.x * blockDim.x) {
        long t = i;
        if (t < N1) {
            long l = t / (256 * 96); long r = t % (256 * 96);
            int j = (int)(r / 96), c = (int)(r % 96);
            float v;
            if (c < 64) v = Win[(l * 256 + j) * 64 + c] * (((j % 63) >= c) ? 1.f : 0.f);
            else        v = Wctx[(l * 256 + j) * 32 + (c - 64)];
            W1[i] = f2bf(v);
        } else if ((t -= N1) < N2) {
            B1[t] = bin[t] + bctx[t];
        } else if ((t -= N2) < N3) {
            int rr = (int)((t / 256) % 256);
            int c = (int)(t % 256);
            float v = Wblk[t] * (((rr % 63) >= (c % 63)) ? 1.f : 0.f);
            WB[t] = f2bf(v);
        } else if ((t -= N3) < N4) {
            long l = t / (3072 * 256); long r = t % (3072 * 256);
            int op = (int)(r / 256), j = (int)(r % 256);
            int fd = op / 48, mm = op % 48;
            float v = 0.f;
            if (mm < 47 && fd > (j % 63))
                v = Wout[(l * 3008 + (long)fd * 47 + mm) * 256 + j];
            WO[t] = f2bf(v);
        } else if ((t -= N4) < N5) {
            long l = t / 3072; int op = (int)(t % 3072);
            int fd = op / 48, mm = op % 48;
            BO[t] = (mm < 47) ? bout[l * 3008 + (long)fd * 47 + mm] : 0.f;
        } else {
            t -= N5;
            long b = t / 32; int p = (int)(t % 32);
            AXE[b * 96 + 64 + p] = f2bf(eta[t]);
        }
    }
}

// ---------------------------------------------------------------------------
// data stats: d_mean (65) + d_sq -> DM[0..64], DM[65]
// ---------------------------------------------------------------------------
__global__ __launch_bounds__(128) void dstat(const float* __restrict__ D,
                                             float* __restrict__ DM)
{
    int j = threadIdx.x;
    float s = 0.f, q = 0.f;
    if (j < 65) {
        for (int m = 0; m < 256; ++m) {
            float v = D[m * 65 + j];
            s += v; q += v * v;
        }
        DM[j] = s * (1.f / 256.f);
    }
    __shared__ float red[128];
    red[j] = q; __syncthreads();
    for (int st = 64; st > 0; st >>= 1) {
        if (j < st) red[j] += red[j + st];
        __syncthreads();
    }
    if (j == 0) DM[65] = red[0] * (1.f / 256.f);
}

// ---------------------------------------------------------------------------
// prep0: flip z -> XF (f32) + AXE cols 0..63 (bf16)
// ---------------------------------------------------------------------------
__global__ __launch_bounds__(256) void prep0(
    const float* __restrict__ z, float* __restrict__ XF, u16* __restrict__ AXE)
{
    size_t gt = (size_t)blockIdx.x * 256 + threadIdx.x;
    size_t b = gt >> 6; int f = (int)(gt & 63);
    float v = z[b * 64 + (63 - f)];
    XF[gt] = v;
    AXE[b * 96 + f] = f2bf(v);
}

// ---------------------------------------------------------------------------
// MFMA GEMM 64x64 tile, double-buffered LDS with register prefetch
// (one barrier per K-step; loads for step k+1 issued before MFMA of step k).
// MODE 0: H=acc+bias;       write H f32, OutB=bf16(relu(H))
// MODE 1: t=relu(acc+bias); write OutB=bf16(t)
// MODE 2: H=Hin+acc+bias;   write H f32, OutB=bf16(relu(H))
// MODE 3: H=Hin+acc+bias;   write OutB=bf16(H)
// ---------------------------------------------------------------------------
template<int MODE>
__global__ __launch_bounds__(256) void gemm_k(
    const u16* __restrict__ A, const u16* __restrict__ Bw,
    const float* __restrict__ bias, const float* __restrict__ Hin,
    float* __restrict__ Hout, u16* __restrict__ OutB, int K)
{
    __shared__ u16 Al[2][64 * 40];
    __shared__ u16 Bl[2][64 * 40];
    const int tid = threadIdx.x;
    const int lane = tid & 63, wv = tid >> 6;
    const int wm = wv >> 1, wn = wv & 1;
    const int fr = lane & 15, kg = lane >> 4;
    const int m0 = blockIdx.x * 64, n0 = blockIdx.y * 64;
    const int sr = tid >> 2, sc = (tid & 3) * 8;

    const u16* gA = A + (size_t)(m0 + sr) * K + sc;
    const u16* gB = Bw + (size_t)(n0 + sr) * K + sc;

    f32x4 acc[2][2];
#pragma unroll
    for (int m = 0; m < 2; ++m)
#pragma unroll
        for (int n = 0; n < 2; ++n) acc[m][n] = (f32x4){0.f, 0.f, 0.f, 0.f};

    *(int4*)&Al[0][sr * 40 + sc] = *(const int4*)gA;
    *(int4*)&Bl[0][sr * 40 + sc] = *(const int4*)gB;
    const int nk = K >> 5;
    for (int ks = 0; ks < nk; ++ks) {
        const int cur = ks & 1;
        int4 pa, pb;
        const bool more = (ks + 1 < nk);
        if (more) {
            pa = *(const int4*)(gA + (ks + 1) * 32);
            pb = *(const int4*)(gB + (ks + 1) * 32);
        }
        __syncthreads();
        bf16x8 af[2], bf[2];
#pragma unroll
        for (int m = 0; m < 2; ++m)
            af[m] = *(const bf16x8*)&Al[cur][(wm * 32 + m * 16 + fr) * 40 + kg * 8];
#pragma unroll
        for (int n = 0; n < 2; ++n)
            bf[n] = *(const bf16x8*)&Bl[cur][(wn * 32 + n * 16 + fr) * 40 + kg * 8];
#pragma unroll
        for (int m = 0; m < 2; ++m)
#pragma unroll
            for (int n = 0; n < 2; ++n)
                acc[m][n] = __builtin_amdgcn_mfma_f32_16x16x32_bf16(af[m], bf[n], acc[m][n], 0, 0, 0);
        if (more) {
            *(int4*)&Al[cur ^ 1][sr * 40 + sc] = pa;
            *(int4*)&Bl[cur ^ 1][sr * 40 + sc] = pb;
        }
    }

#pragma unroll
    for (int m = 0; m < 2; ++m) {
#pragma unroll
        for (int n = 0; n < 2; ++n) {
            int rg = m0 + wm * 32 + m * 16 + kg * 4;
            int cg = n0 + wn * 32 + n * 16 + fr;
            float bs = bias[cg];
#pragma unroll
            for (int j = 0; j < 4; ++j) {
                size_t idx = (size_t)(rg + j) * 256 + cg;
                float v = acc[m][n][j] + bs;
                if constexpr (MODE == 0) {
                    Hout[idx] = v; OutB[idx] = f2bf(fmaxf(v, 0.f));
                } else if constexpr (MODE == 1) {
                    OutB[idx] = f2bf(fmaxf(v, 0.f));
                } else if constexpr (MODE == 2) {
                    float h = Hin[idx] + v; Hout[idx] = h; OutB[idx] = f2bf(fmaxf(h, 0.f));
                } else {
                    float h = Hin[idx] + v; OutB[idx] = f2bf(h);
                }
            }
        }
    }
}

// ---------------------------------------------------------------------------
// Out-GEMM (128x96 tile, K=256) + fused RQS spline.
// Swapped-operand MFMA: lane holds (batch row = fr, 4 consecutive cols) ->
// b64 LDS dump (pitch 104), b128 spline reads, one-pass knot/select loop,
// native transcendentals. Double-buffered staging with reg prefetch.
// ---------------------------------------------------------------------------
__global__ __launch_bounds__(256) void gemm_out_spline(
    const u16* __restrict__ A, const u16* __restrict__ Wo,
    const float* __restrict__ bo, const float* __restrict__ XF,
    float* __restrict__ Xn, float* __restrict__ XFnext, u16* __restrict__ AXE,
    float* __restrict__ LDP, int first)
{
    __shared__ u16 SM[17920];            // 35840 B: A dbuf | B dbuf; aliased by dump
    const int tid = threadIdx.x;
    const int lane = tid & 63, wv = tid >> 6;
    const int wm = wv >> 1, wn = wv & 1;
    const int fr = lane & 15, kg = lane >> 4;
    const int m0 = blockIdx.x * 128, n0 = blockIdx.y * 96;
    const int sr = tid >> 2, sc = (tid & 3) * 8;

    u16* Abase = SM;                     // 2 x 5120 u16
    u16* Bbase = SM + 10240;             // 2 x 3840 u16

    const u16* gA = A  + (size_t)(m0 + sr) * 256 + sc;   // rows sr, sr+64
    const u16* gB = Wo + (size_t)(n0 + sr) * 256 + sc;   // rows sr (+64 if tid<128)

    f32x4 acc[4][3];
#pragma unroll
    for (int m = 0; m < 4; ++m)
#pragma unroll
        for (int n = 0; n < 3; ++n) acc[m][n] = (f32x4){0.f, 0.f, 0.f, 0.f};

    *(int4*)&Abase[sr * 40 + sc]        = *(const int4*)gA;
    *(int4*)&Abase[(sr + 64) * 40 + sc] = *(const int4*)(gA + 64 * 256);
    *(int4*)&Bbase[sr * 40 + sc]        = *(const int4*)gB;
    if (tid < 128)
        *(int4*)&Bbase[(sr + 64) * 40 + sc] = *(const int4*)(gB + 64 * 256);

    for (int ks = 0; ks < 8; ++ks) {
        const int cur = ks & 1;
        int4 pa0, pa1, pb0, pb1;
        const bool more = (ks < 7);
        if (more) {
            pa0 = *(const int4*)(gA + (ks + 1) * 32);
            pa1 = *(const int4*)(gA + 64 * 256 + (ks + 1) * 32);
            pb0 = *(const int4*)(gB + (ks + 1) * 32);
            if (tid < 128) pb1 = *(const int4*)(gB + 64 * 256 + (ks + 1) * 32);
        }
        __syncthreads();
        const u16* Ac = Abase + cur * 5120;
        const u16* Bc = Bbase + cur * 3840;
        bf16x8 af[4], bf[3];
#pragma unroll
        for (int m = 0; m < 4; ++m)
            af[m] = *(const bf16x8*)&Ac[(wm * 64 + m * 16 + fr) * 40 + kg * 8];
#pragma unroll
        for (int n = 0; n < 3; ++n)
            bf[n] = *(const bf16x8*)&Bc[(wn * 48 + n * 16 + fr) * 40 + kg * 8];
#pragma unroll
        for (int m = 0; m < 4; ++m)
#pragma unroll
            for (int n = 0; n < 3; ++n)
                acc[m][n] = __builtin_amdgcn_mfma_f32_16x16x32_bf16(bf[n], af[m], acc[m][n], 0, 0, 0);
        if (more) {
            u16* An = Abase + (cur ^ 1) * 5120;
            u16* Bn = Bbase + (cur ^ 1) * 3840;
            *(int4*)&An[sr * 40 + sc]        = pa0;
            *(int4*)&An[(sr + 64) * 40 + sc] = pa1;
            *(int4*)&Bn[sr * 40 + sc]        = pb0;
            if (tid < 128) *(int4*)&Bn[(sr + 64) * 40 + sc] = pb1;
        }
    }
    __syncthreads();   // all frag reads done before dump aliases the buffers

    // dump acc(+bias) as bf16, pitch 104 u16, b64 stores (4 cols per lane)
#pragma unroll
    for (int m = 0; m < 4; ++m) {
        const int row = wm * 64 + m * 16 + fr;
#pragma unroll
        for (int n = 0; n < 3; ++n) {
            const int c0 = wn * 48 + n * 16 + kg * 4;
            const float4 bs = *(const float4*)&bo[n0 + c0];
            short4 q;
            q.x = (short)f2bf(acc[m][n][0] + bs.x);
            q.y = (short)f2bf(acc[m][n][1] + bs.y);
            q.z = (short)f2bf(acc[m][n][2] + bs.z);
            q.w = (short)f2bf(acc[m][n][3] + bs.w);
            *(short4*)&SM[row * 104 + c0] = q;
        }
    }
    __syncthreads();

    // ---- RQS spline: one thread per (row, feature); 256 = 128 x 2 ----
    const int r = tid >> 1, fi = tid & 1;
    const int b = m0 + r;
    const int fg = blockIdx.y * 2 + fi;
    const u16* o_ = &SM[r * 104 + fi * 48];
    bf16x8 v0 = *(const bf16x8*)(o_);
    bf16x8 v1 = *(const bf16x8*)(o_ + 8);
    bf16x8 v2 = *(const bf16x8*)(o_ + 16);
    bf16x8 v3 = *(const bf16x8*)(o_ + 24);
    bf16x8 v4 = *(const bf16x8*)(o_ + 32);
    bf16x8 v5 = *(const bf16x8*)(o_ + 40);

    float xin = XF[(size_t)b * 64 + fg];
    bool inside = (xin >= -10.f) && (xin <= 10.f);
    float xs = fminf(fmaxf(xin, -10.f), 10.f);

    float ew[16], eh[16], ud[15];
#pragma unroll
    for (int i = 0; i < 8; ++i) {
        ew[i]     = bf2f((u16)v0[i]) * 0.0625f;
        ew[8 + i] = bf2f((u16)v1[i]) * 0.0625f;
        eh[i]     = bf2f((u16)v2[i]) * 0.0625f;
        eh[8 + i] = bf2f((u16)v3[i]) * 0.0625f;
    }
#pragma unroll
    for (int i = 0; i < 8; ++i) ud[i] = bf2f((u16)v4[i]);
#pragma unroll
    for (int i = 0; i < 7; ++i) ud[8 + i] = bf2f((u16)v5[i]);

    float mw = ew[0], mh = eh[0];
#pragma unroll
    for (int i = 1; i < 16; ++i) { mw = fmaxf(mw, ew[i]); mh = fmaxf(mh, eh[i]); }
    float sw = 0.f, sh = 0.f;
#pragma unroll
    for (int i = 0; i < 16; ++i) {
        ew[i] = __expf(ew[i] - mw); sw += ew[i];
        eh[i] = __expf(eh[i] - mh); sh += eh[i];
    }
    const float kw = 20.f * (1.f - 1.6e-7f) / sw;
    const float kh = 20.f * (1.f - 1.6e-7f) / sh;

    // one-pass knot cumsum + bin selection (knots increasing; last k with
    // cw_k <= xs wins = idx, capped at 15)
    float cwk = -10.f, chk = -10.f;
    float icw = -10.f, ich = -10.f, iw = 1.f, ih = 1.f, udl = 0.f, udr = 0.f;
    int selk = 0;
#pragma unroll
    for (int k = 0; k < 16; ++k) {
        const float cw1 = (k == 15) ? 10.f : cwk + (2e-7f + kw * ew[k]);
        const float ch1 = (k == 15) ? 10.f : chk + (2e-7f + kh * eh[k]);
        if (xs >= cwk) {
            selk = k;
            icw = cwk; iw = cw1 - cwk;
            ich = chk; ih = ch1 - chk;
            udl = (k >= 1)  ? ud[k - 1] : 0.f;
            udr = (k <= 14) ? ud[k]     : 0.f;
        }
        cwk = cw1; chk = ch1;
    }
    float d0 = (selk == 0)  ? 1.f : 1e-8f + splusf(udl);
    float d1 = (selk == 15) ? 1.f : 1e-8f + splusf(udr);
    float delta = ih / iw;
    float t = (xs - icw) / iw;
    float tt = t * (1.f - t);
    float denom = delta + (d0 + d1 - 2.f * delta) * tt;
    float y = ich + ih * (delta * t * t + d0 * tt) / denom;
    float omt = 1.f - t;
    float dnum = delta * delta * (d1 * t * t + 2.f * delta * tt + d0 * omt * omt);
    float ldv = __logf(dnum) - 2.f * __logf(denom);
    if (!inside) { y = xin; ldv = 0.f; }

    Xn[(size_t)b * 64 + fg] = y;
    XFnext[(size_t)b * 64 + (63 - fg)] = y;
    AXE[(size_t)b * 96 + (63 - fg)] = f2bf(y);

    float other = __shfl_xor(ldv, 1);
    if (fi == 0) {
        size_t o = (size_t)b * 32 + blockIdx.y;
        float v = ldv + other;
        LDP[o] = first ? v : (LDP[o] + v);
    }
}

// ---------------------------------------------------------------------------
// finals: stick-breaking + per-sample objective, then reduction
// ---------------------------------------------------------------------------
__global__ __launch_bounds__(256) void final1(
    const float* __restrict__ X, const float* __restrict__ z,
    const float* __restrict__ LDP, const float* __restrict__ DM,
    float* __restrict__ PART)
{
    int tid = threadIdx.x;
    int b = blockIdx.x * 256 + tid;
    float ldt = 0.f;
    for (int g = 0; g < 32; ++g) ldt += LDP[(size_t)b * 32 + g];
    float pre = 0.f, lvs = 0.f, wls = 0.f, lp = 0.f, tdm = 0.f, tsq = 0.f;
    const float LCLIP = -23.02585093f;   // ln(1e-10)
    for (int i = 0; i < 64; ++i) {
        float xi = X[(size_t)b * 64 + i];
        float lv = -splusf(-xi), l1 = -splusf(xi);
        float lt = lv + pre;
        float th = __expf(lt);
        lp += fmaxf(lt, LCLIP);          // log(max(exp(lt),1e-10))
        tdm += th * DM[i]; tsq += th * th;
        lvs += lv; wls += (float)(64 - i) * l1;
        pre += l1;
    }
    float th = __expf(pre);
    lp += fmaxf(pre, LCLIP); tdm += th * DM[64]; tsq += th * th;
    float zs = 0.f;
    for (int i = 0; i < 64; ++i) { float zz = z[(size_t)b * 64 + i]; zs += zz * zz; }
    float logqz = -0.5f * zs - 58.812066f;
    float log_q = logqz - (ldt + lvs + wls);
    float log_lik = -0.5f * (DM[65] - 2.f * tdm + tsq);
    float val = log_q - lp - log_lik;

    __shared__ float red[256];
    red[tid] = val; __syncthreads();
    for (int s = 128; s > 0; s >>= 1) {
        if (tid < s) red[tid] += red[tid + s];
        __syncthreads();
    }
    if (tid == 0) PART[blockIdx.x] = red[0];
}

__global__ __launch_bounds__(64) void final2(const float* __restrict__ PART,
                                             float* __restrict__ out)
{
    int tid = threadIdx.x;
    float s = (tid < 32) ? PART[tid] : 0.f;
    for (int o = 16; o > 0; o >>= 1) s += __shfl_down(s, o);
    if (tid == 0) out[0] = s * (1.f / 8192.f);
}

// ---------------------------------------------------------------------------
extern "C" void kernel_launch(void* const* d_in, const int* in_sizes, int n_in,
                              void* d_out, int out_size, void* d_ws, size_t ws_size,
                              hipStream_t stream)
{
    (void)in_sizes; (void)n_in; (void)out_size; (void)ws_size;
    const float* z    = (const float*)d_in[0];
    const float* eta  = (const float*)d_in[1];
    const float* dat  = (const float*)d_in[2];
    const float* Win  = (const float*)d_in[3];
    const float* bin  = (const float*)d_in[4];
    const float* Wctx = (const float*)d_in[5];
    const float* bctx = (const float*)d_in[6];
    const float* Wblk = (const float*)d_in[7];
    const float* bblk = (const float*)d_in[8];
    const float* Wout = (const float*)d_in[9];
    const float* bout = (const float*)d_in[10];
    float* out = (float*)d_out;

    char* w = (char*)d_ws;
    size_t off = 0;
    auto alloc = [&](size_t bytes) {
        void* p = w + off;
        off += (bytes + 255) & ~(size_t)255;
        return p;
    };
    u16*   W1  = (u16*)  alloc(8L * 256 * 96 * 2);
    float* B1  = (float*)alloc(8L * 256 * 4);
    u16*   WB  = (u16*)  alloc(8L * 4 * 256 * 256 * 2);
    u16*   WO  = (u16*)  alloc(8L * 3072 * 256 * 2);
    float* BO  = (float*)alloc(8L * 3072 * 4);
    u16*   AXE = (u16*)  alloc(8192L * 96 * 2);
    float* XFa = (float*)alloc(8192L * 64 * 4);
    float* XFb = (float*)alloc(8192L * 64 * 4);
    float* XC  = (float*)alloc(8192L * 64 * 4);
    float* H   = (float*)alloc(8192L * 256 * 4);
    u16*   HB  = (u16*)  alloc(8192L * 256 * 2);
    u16*   TB  = (u16*)  alloc(8192L * 256 * 2);
    float* LDP = (float*)alloc(8192L * 32 * 4);
    float* DM  = (float*)alloc(66 * 4);
    float* PART= (float*)alloc(64 * 4);

    setup_w<<<dim3(2048), dim3(256), 0, stream>>>(
        Win, bin, Wctx, bctx, Wblk, Wout, bout, eta, W1, B1, WB, WO, BO, AXE);
    dstat<<<dim3(1), dim3(128), 0, stream>>>(dat, DM);
    prep0<<<dim3(2048), dim3(256), 0, stream>>>(z, XFa, AXE);

    for (int l = 0; l < 8; ++l) {
        float* XFin  = (l & 1) ? XFb : XFa;
        float* XFout = (l & 1) ? XFa : XFb;
        gemm_k<0><<<dim3(128, 4), dim3(256), 0, stream>>>(
            AXE, W1 + (size_t)l * 256 * 96, B1 + l * 256,
            (const float*)nullptr, H, HB, 96);
        gemm_k<1><<<dim3(128, 4), dim3(256), 0, stream>>>(
            HB, WB + ((size_t)l * 4 + 0) * 65536, bblk + (l * 4 + 0) * 256,
            (const float*)nullptr, (float*)nullptr, TB, 256);
        gemm_k<2><<<dim3(128, 4), dim3(256), 0, stream>>>(
            TB, WB + ((size_t)l * 4 + 1) * 65536, bblk + (l * 4 + 1) * 256,
            H, H, HB, 256);
        gemm_k<1><<<dim3(128, 4), dim3(256), 0, stream>>>(
            HB, WB + ((size_t)l * 4 + 2) * 65536, bblk + (l * 4 + 2) * 256,
            (const float*)nullptr, (float*)nullptr, TB, 256);
        gemm_k<3><<<dim3(128, 4), dim3(256), 0, stream>>>(
            TB, WB + ((size_t)l * 4 + 3) * 65536, bblk + (l * 4 + 3) * 256,
            H, (float*)nullptr, HB, 256);
        gemm_out_spline<<<dim3(64, 32), dim3(256), 0, stream>>>(
            HB, WO + (size_t)l * 3072 * 256, BO + l * 3072, XFin,
            XC, XFout, AXE, LDP, (l == 0) ? 1 : 0);
    }
    final1<<<dim3(32), dim3(256), 0, stream>>>(XC, z, LDP, DM, PART);
    final2<<<dim3(1), dim3(64), 0, stream>>>(PART, out);
}

// Round 4
// 420.929 us; speedup vs baseline: 1.6744x; 1.1931x over previous
//
#include <hip/hip_runtime.h>
#include <math.h>

typedef float f32x4 __attribute__((ext_vector_type(4)));
typedef short bf16x8 __attribute__((ext_vector_type(8)));
typedef unsigned short u16;

__device__ __forceinline__ u16 f2bf(float f) {
    union { float f; unsigned u; } v; v.f = f;
    return (u16)((v.u + 0x7FFFu + ((v.u >> 16) & 1u)) >> 16);
}
__device__ __forceinline__ float bf2f(u16 h) {
    union { unsigned u; float f; } v; v.u = ((unsigned)h) << 16;
    return v.f;
}
__device__ __forceinline__ float splusf(float x) {
    return fmaxf(x, 0.f) + __logf(1.f + __expf(-fabsf(x)));
}

// ---------------------------------------------------------------------------
// setup: build masked bf16 weights (+padded Wo), fused biases, eta->AXE cols
// ---------------------------------------------------------------------------
__global__ __launch_bounds__(256) void setup_w(
    const float* __restrict__ Win, const float* __restrict__ bin,
    const float* __restrict__ Wctx, const float* __restrict__ bctx,
    const float* __restrict__ Wblk, const float* __restrict__ Wout,
    const float* __restrict__ bout, const float* __restrict__ eta,
    u16* __restrict__ W1, float* __restrict__ B1, u16* __restrict__ WB,
    u16* __restrict__ WO, float* __restrict__ BO, u16* __restrict__ AXE)
{
    const long N1 = 8L * 256 * 96;
    const long N2 = 8L * 256;
    const long N3 = 8L * 4 * 256 * 256;
    const long N4 = 8L * 3072 * 256;
    const long N5 = 8L * 3072;
    const long N6 = 8192L * 32;
    const long tot = N1 + N2 + N3 + N4 + N5 + N6;
    for (long i = (long)blockIdx.x * blockDim.x + threadIdx.x; i < tot;
         i += (long)gridDim.x * blockDim.x) {
        long t = i;
        if (t < N1) {
            long l = t / (256 * 96); long r = t % (256 * 96);
            int j = (int)(r / 96), c = (int)(r % 96);
            float v;
            if (c < 64) v = Win[(l * 256 + j) * 64 + c] * (((j % 63) >= c) ? 1.f : 0.f);
            else        v = Wctx[(l * 256 + j) * 32 + (c - 64)];
            W1[i] = f2bf(v);
        } else if ((t -= N1) < N2) {
            B1[t] = bin[t] + bctx[t];
        } else if ((t -= N2) < N3) {
            int rr = (int)((t / 256) % 256);
            int c = (int)(t % 256);
            float v = Wblk[t] * (((rr % 63) >= (c % 63)) ? 1.f : 0.f);
            WB[t] = f2bf(v);
        } else if ((t -= N3) < N4) {
            long l = t / (3072 * 256); long r = t % (3072 * 256);
            int op = (int)(r / 256), j = (int)(r % 256);
            int fd = op / 48, mm = op % 48;
            float v = 0.f;
            if (mm < 47 && fd > (j % 63))
                v = Wout[(l * 3008 + (long)fd * 47 + mm) * 256 + j];
            WO[t] = f2bf(v);
        } else if ((t -= N4) < N5) {
            long l = t / 3072; int op = (int)(t % 3072);
            int fd = op / 48, mm = op % 48;
            BO[t] = (mm < 47) ? bout[l * 3008 + (long)fd * 47 + mm] : 0.f;
        } else {
            t -= N5;
            long b = t / 32; int p = (int)(t % 32);
            AXE[b * 96 + 64 + p] = f2bf(eta[t]);
        }
    }
}

// ---------------------------------------------------------------------------
// data stats
// ---------------------------------------------------------------------------
__global__ __launch_bounds__(128) void dstat(const float* __restrict__ D,
                                             float* __restrict__ DM)
{
    int j = threadIdx.x;
    float s = 0.f, q = 0.f;
    if (j < 65) {
        for (int m = 0; m < 256; ++m) {
            float v = D[m * 65 + j];
            s += v; q += v * v;
        }
        DM[j] = s * (1.f / 256.f);
    }
    __shared__ float red[128];
    red[j] = q; __syncthreads();
    for (int st = 64; st > 0; st >>= 1) {
        if (j < st) red[j] += red[j + st];
        __syncthreads();
    }
    if (j == 0) DM[65] = red[0] * (1.f / 256.f);
}

// ---------------------------------------------------------------------------
// prep0: flip z -> XF (f32) + AXE cols 0..63 (bf16)
// ---------------------------------------------------------------------------
__global__ __launch_bounds__(256) void prep0(
    const float* __restrict__ z, float* __restrict__ XF, u16* __restrict__ AXE)
{
    size_t gt = (size_t)blockIdx.x * 256 + threadIdx.x;
    size_t b = gt >> 6; int f = (int)(gt & 63);
    float v = z[b * 64 + (63 - f)];
    XF[gt] = v;
    AXE[b * 96 + f] = f2bf(v);
}

// ---------------------------------------------------------------------------
// fused_mid: one kernel per layer for all 5 mid GEMMs.
// Grid 256 blocks x 32 batch rows, 512 threads (8 waves, wave owns 32 chans).
// H stays in VGPR fragments across stages; activations bounce via LDS tile
// (pitch 264); weights stream L2->LDS double-buffered (pitch 40, K-slice 32).
// ---------------------------------------------------------------------------
template<int NK>
__device__ __forceinline__ void mid_stage(
    const u16* __restrict__ Wsrc, int wpitch,
    u16* __restrict__ Wq0, u16* __restrict__ Wq1,
    const u16* __restrict__ act,
    int tid, int fr, int kg, int ch0, f32x4 (&acc)[2][2])
{
    const int swr = tid >> 1;
    const int swp = (tid & 1) << 4;
    const u16* gW = Wsrc + (size_t)swr * wpitch + swp;

    // slice 0 -> Wq0
    *(int4*)&Wq0[swr * 40 + swp]     = *(const int4*)(gW);
    *(int4*)&Wq0[swr * 40 + swp + 8] = *(const int4*)(gW + 8);

#pragma unroll
    for (int ks = 0; ks < NK; ++ks) {
        const u16* cbuf = (ks & 1) ? Wq1 : Wq0;
        u16*       nbuf = (ks & 1) ? Wq0 : Wq1;
        int4 p0, p1;
        const bool more = (ks + 1 < NK);
        if (more) {
            p0 = *(const int4*)(gW + (ks + 1) * 32);
            p1 = *(const int4*)(gW + (ks + 1) * 32 + 8);
        }
        __syncthreads();
        bf16x8 wf0 = *(const bf16x8*)&cbuf[(ch0 + fr) * 40 + kg * 8];
        bf16x8 wf1 = *(const bf16x8*)&cbuf[(ch0 + 16 + fr) * 40 + kg * 8];
        bf16x8 af0 = *(const bf16x8*)&act[fr * 264 + ks * 32 + kg * 8];
        bf16x8 af1 = *(const bf16x8*)&act[(16 + fr) * 264 + ks * 32 + kg * 8];
        acc[0][0] = __builtin_amdgcn_mfma_f32_16x16x32_bf16(wf0, af0, acc[0][0], 0, 0, 0);
        acc[0][1] = __builtin_amdgcn_mfma_f32_16x16x32_bf16(wf0, af1, acc[0][1], 0, 0, 0);
        acc[1][0] = __builtin_amdgcn_mfma_f32_16x16x32_bf16(wf1, af0, acc[1][0], 0, 0, 0);
        acc[1][1] = __builtin_amdgcn_mfma_f32_16x16x32_bf16(wf1, af1, acc[1][1], 0, 0, 0);
        if (more) {
            *(int4*)&nbuf[swr * 40 + swp]     = p0;
            *(int4*)&nbuf[swr * 40 + swp + 8] = p1;
        }
    }
    __syncthreads();   // all LDS reads done; caller may overwrite act
}

__global__ __launch_bounds__(512) void fused_mid(
    const u16* __restrict__ AXE, const u16* __restrict__ W1l,
    const float* __restrict__ B1l, const u16* __restrict__ WBl,
    const float* __restrict__ bbl, u16* __restrict__ HB)
{
    __shared__ u16 Wq0[256 * 40];
    __shared__ u16 Wq1[256 * 40];
    __shared__ u16 act[32 * 264];
    const int tid = threadIdx.x;
    const int lane = tid & 63;
    const int wv = tid >> 6;
    const int fr = lane & 15, kg = lane >> 4;
    const int b0 = blockIdx.x * 32;
    const int ch0 = wv * 32;

    // stage-0 activations: AXE rows b0..b0+31 (96 u16 each)
    for (int i = tid; i < 384; i += 512) {
        int row = i / 12, part = i - row * 12;
        *(int4*)&act[row * 264 + part * 8] =
            *(const int4*)&AXE[(size_t)(b0 + row) * 96 + part * 8];
    }

    f32x4 H[2][2], T[2][2];

    auto zeroT = [&]() {
#pragma unroll
        for (int m = 0; m < 2; ++m)
#pragma unroll
            for (int n = 0; n < 2; ++n) T[m][n] = (f32x4){0.f, 0.f, 0.f, 0.f};
    };
    // mode 0: H=T+b, act=relu(H); 1: act=relu(T+b); 2: H+=T+b, act=relu(H);
    // mode 3: H+=T+b, HB=bf16(H) global
    auto epi = [&](const float* bias, int mode) {
#pragma unroll
        for (int m = 0; m < 2; ++m) {
            const int cb = ch0 + m * 16 + kg * 4;
            const float4 bs = *(const float4*)&bias[cb];
#pragma unroll
            for (int n = 0; n < 2; ++n) {
                f32x4 v = T[m][n];
                v[0] += bs.x; v[1] += bs.y; v[2] += bs.z; v[3] += bs.w;
                if (mode == 0) H[m][n] = v;
                if (mode == 2 || mode == 3) {
                    H[m][n][0] += v[0]; H[m][n][1] += v[1];
                    H[m][n][2] += v[2]; H[m][n][3] += v[3];
                    v = H[m][n];
                }
                short4 q;
                if (mode != 3) {
                    q.x = (short)f2bf(fmaxf(v[0], 0.f));
                    q.y = (short)f2bf(fmaxf(v[1], 0.f));
                    q.z = (short)f2bf(fmaxf(v[2], 0.f));
                    q.w = (short)f2bf(fmaxf(v[3], 0.f));
                    *(short4*)&act[(n * 16 + fr) * 264 + cb] = q;
                } else {
                    q.x = (short)f2bf(v[0]); q.y = (short)f2bf(v[1]);
                    q.z = (short)f2bf(v[2]); q.w = (short)f2bf(v[3]);
                    *(short4*)&HB[(size_t)(b0 + n * 16 + fr) * 256 + cb] = q;
                }
            }
        }
    };

    zeroT();
    mid_stage<3>(W1l, 96, Wq0, Wq1, act, tid, fr, kg, ch0, T);
    epi(B1l, 0);
    zeroT();
    mid_stage<8>(WBl, 256, Wq0, Wq1, act, tid, fr, kg, ch0, T);
    epi(bbl, 1);
    zeroT();
    mid_stage<8>(WBl + 65536, 256, Wq0, Wq1, act, tid, fr, kg, ch0, T);
    epi(bbl + 256, 2);
    zeroT();
    mid_stage<8>(WBl + 2 * 65536, 256, Wq0, Wq1, act, tid, fr, kg, ch0, T);
    epi(bbl + 2 * 256, 1);
    zeroT();
    mid_stage<8>(WBl + 3 * 65536, 256, Wq0, Wq1, act, tid, fr, kg, ch0, T);
    epi(bbl + 3 * 256, 3);
}

// ---------------------------------------------------------------------------
// Out-GEMM (128x96 tile, K=256) + fused RQS spline (unchanged from R3).
// ---------------------------------------------------------------------------
__global__ __launch_bounds__(256) void gemm_out_spline(
    const u16* __restrict__ A, const u16* __restrict__ Wo,
    const float* __restrict__ bo, const float* __restrict__ XF,
    float* __restrict__ Xn, float* __restrict__ XFnext, u16* __restrict__ AXE,
    float* __restrict__ LDP, int first)
{
    __shared__ u16 SM[17920];
    const int tid = threadIdx.x;
    const int lane = tid & 63, wv = tid >> 6;
    const int wm = wv >> 1, wn = wv & 1;
    const int fr = lane & 15, kg = lane >> 4;
    const int m0 = blockIdx.x * 128, n0 = blockIdx.y * 96;
    const int sr = tid >> 2, sc = (tid & 3) * 8;

    u16* Abase = SM;
    u16* Bbase = SM + 10240;

    const u16* gA = A  + (size_t)(m0 + sr) * 256 + sc;
    const u16* gB = Wo + (size_t)(n0 + sr) * 256 + sc;

    f32x4 acc[4][3];
#pragma unroll
    for (int m = 0; m < 4; ++m)
#pragma unroll
        for (int n = 0; n < 3; ++n) acc[m][n] = (f32x4){0.f, 0.f, 0.f, 0.f};

    *(int4*)&Abase[sr * 40 + sc]        = *(const int4*)gA;
    *(int4*)&Abase[(sr + 64) * 40 + sc] = *(const int4*)(gA + 64 * 256);
    *(int4*)&Bbase[sr * 40 + sc]        = *(const int4*)gB;
    if (tid < 128)
        *(int4*)&Bbase[(sr + 64) * 40 + sc] = *(const int4*)(gB + 64 * 256);

    for (int ks = 0; ks < 8; ++ks) {
        const int cur = ks & 1;
        int4 pa0, pa1, pb0, pb1;
        const bool more = (ks < 7);
        if (more) {
            pa0 = *(const int4*)(gA + (ks + 1) * 32);
            pa1 = *(const int4*)(gA + 64 * 256 + (ks + 1) * 32);
            pb0 = *(const int4*)(gB + (ks + 1) * 32);
            if (tid < 128) pb1 = *(const int4*)(gB + 64 * 256 + (ks + 1) * 32);
        }
        __syncthreads();
        const u16* Ac = Abase + cur * 5120;
        const u16* Bc = Bbase + cur * 3840;
        bf16x8 af[4], bf[3];
#pragma unroll
        for (int m = 0; m < 4; ++m)
            af[m] = *(const bf16x8*)&Ac[(wm * 64 + m * 16 + fr) * 40 + kg * 8];
#pragma unroll
        for (int n = 0; n < 3; ++n)
            bf[n] = *(const bf16x8*)&Bc[(wn * 48 + n * 16 + fr) * 40 + kg * 8];
#pragma unroll
        for (int m = 0; m < 4; ++m)
#pragma unroll
            for (int n = 0; n < 3; ++n)
                acc[m][n] = __builtin_amdgcn_mfma_f32_16x16x32_bf16(bf[n], af[m], acc[m][n], 0, 0, 0);
        if (more) {
            u16* An = Abase + (cur ^ 1) * 5120;
            u16* Bn = Bbase + (cur ^ 1) * 3840;
            *(int4*)&An[sr * 40 + sc]        = pa0;
            *(int4*)&An[(sr + 64) * 40 + sc] = pa1;
            *(int4*)&Bn[sr * 40 + sc]        = pb0;
            if (tid < 128) *(int4*)&Bn[(sr + 64) * 40 + sc] = pb1;
        }
    }
    __syncthreads();

#pragma unroll
    for (int m = 0; m < 4; ++m) {
        const int row = wm * 64 + m * 16 + fr;
#pragma unroll
        for (int n = 0; n < 3; ++n) {
            const int c0 = wn * 48 + n * 16 + kg * 4;
            const float4 bs = *(const float4*)&bo[n0 + c0];
            short4 q;
            q.x = (short)f2bf(acc[m][n][0] + bs.x);
            q.y = (short)f2bf(acc[m][n][1] + bs.y);
            q.z = (short)f2bf(acc[m][n][2] + bs.z);
            q.w = (short)f2bf(acc[m][n][3] + bs.w);
            *(short4*)&SM[row * 104 + c0] = q;
        }
    }
    __syncthreads();

    const int r = tid >> 1, fi = tid & 1;
    const int b = m0 + r;
    const int fg = blockIdx.y * 2 + fi;
    const u16* o_ = &SM[r * 104 + fi * 48];
    bf16x8 v0 = *(const bf16x8*)(o_);
    bf16x8 v1 = *(const bf16x8*)(o_ + 8);
    bf16x8 v2 = *(const bf16x8*)(o_ + 16);
    bf16x8 v3 = *(const bf16x8*)(o_ + 24);
    bf16x8 v4 = *(const bf16x8*)(o_ + 32);
    bf16x8 v5 = *(const bf16x8*)(o_ + 40);

    float xin = XF[(size_t)b * 64 + fg];
    bool inside = (xin >= -10.f) && (xin <= 10.f);
    float xs = fminf(fmaxf(xin, -10.f), 10.f);

    float ew[16], eh[16], ud[15];
#pragma unroll
    for (int i = 0; i < 8; ++i) {
        ew[i]     = bf2f((u16)v0[i]) * 0.0625f;
        ew[8 + i] = bf2f((u16)v1[i]) * 0.0625f;
        eh[i]     = bf2f((u16)v2[i]) * 0.0625f;
        eh[8 + i] = bf2f((u16)v3[i]) * 0.0625f;
    }
#pragma unroll
    for (int i = 0; i < 8; ++i) ud[i] = bf2f((u16)v4[i]);
#pragma unroll
    for (int i = 0; i < 7; ++i) ud[8 + i] = bf2f((u16)v5[i]);

    float mw = ew[0], mh = eh[0];
#pragma unroll
    for (int i = 1; i < 16; ++i) { mw = fmaxf(mw, ew[i]); mh = fmaxf(mh, eh[i]); }
    float sw = 0.f, sh = 0.f;
#pragma unroll
    for (int i = 0; i < 16; ++i) {
        ew[i] = __expf(ew[i] - mw); sw += ew[i];
        eh[i] = __expf(eh[i] - mh); sh += eh[i];
    }
    const float kw = 20.f * (1.f - 1.6e-7f) / sw;
    const float kh = 20.f * (1.f - 1.6e-7f) / sh;

    float cwk = -10.f, chk = -10.f;
    float icw = -10.f, ich = -10.f, iw = 1.f, ih = 1.f, udl = 0.f, udr = 0.f;
    int selk = 0;
#pragma unroll
    for (int k = 0; k < 16; ++k) {
        const float cw1 = (k == 15) ? 10.f : cwk + (2e-7f + kw * ew[k]);
        const float ch1 = (k == 15) ? 10.f : chk + (2e-7f + kh * eh[k]);
        if (xs >= cwk) {
            selk = k;
            icw = cwk; iw = cw1 - cwk;
            ich = chk; ih = ch1 - chk;
            udl = (k >= 1)  ? ud[k - 1] : 0.f;
            udr = (k <= 14) ? ud[k]     : 0.f;
        }
        cwk = cw1; chk = ch1;
    }
    float d0 = (selk == 0)  ? 1.f : 1e-8f + splusf(udl);
    float d1 = (selk == 15) ? 1.f : 1e-8f + splusf(udr);
    float delta = ih / iw;
    float t = (xs - icw) / iw;
    float tt = t * (1.f - t);
    float denom = delta + (d0 + d1 - 2.f * delta) * tt;
    float y = ich + ih * (delta * t * t + d0 * tt) / denom;
    float omt = 1.f - t;
    float dnum = delta * delta * (d1 * t * t + 2.f * delta * tt + d0 * omt * omt);
    float ldv = __logf(dnum) - 2.f * __logf(denom);
    if (!inside) { y = xin; ldv = 0.f; }

    Xn[(size_t)b * 64 + fg] = y;
    XFnext[(size_t)b * 64 + (63 - fg)] = y;
    AXE[(size_t)b * 96 + (63 - fg)] = f2bf(y);

    float other = __shfl_xor(ldv, 1);
    if (fi == 0) {
        size_t o = (size_t)b * 32 + blockIdx.y;
        float v = ldv + other;
        LDP[o] = first ? v : (LDP[o] + v);
    }
}

// ---------------------------------------------------------------------------
// finals
// ---------------------------------------------------------------------------
__global__ __launch_bounds__(256) void final1(
    const float* __restrict__ X, const float* __restrict__ z,
    const float* __restrict__ LDP, const float* __restrict__ DM,
    float* __restrict__ PART)
{
    int tid = threadIdx.x;
    int b = blockIdx.x * 256 + tid;
    float ldt = 0.f;
    for (int g = 0; g < 32; ++g) ldt += LDP[(size_t)b * 32 + g];
    float pre = 0.f, lvs = 0.f, wls = 0.f, lp = 0.f, tdm = 0.f, tsq = 0.f;
    const float LCLIP = -23.02585093f;
    for (int i = 0; i < 64; ++i) {
        float xi = X[(size_t)b * 64 + i];
        float lv = -splusf(-xi), l1 = -splusf(xi);
        float lt = lv + pre;
        float th = __expf(lt);
        lp += fmaxf(lt, LCLIP);
        tdm += th * DM[i]; tsq += th * th;
        lvs += lv; wls += (float)(64 - i) * l1;
        pre += l1;
    }
    float th = __expf(pre);
    lp += fmaxf(pre, LCLIP); tdm += th * DM[64]; tsq += th * th;
    float zs = 0.f;
    for (int i = 0; i < 64; ++i) { float zz = z[(size_t)b * 64 + i]; zs += zz * zz; }
    float logqz = -0.5f * zs - 58.812066f;
    float log_q = logqz - (ldt + lvs + wls);
    float log_lik = -0.5f * (DM[65] - 2.f * tdm + tsq);
    float val = log_q - lp - log_lik;

    __shared__ float red[256];
    red[tid] = val; __syncthreads();
    for (int s = 128; s > 0; s >>= 1) {
        if (tid < s) red[tid] += red[tid + s];
        __syncthreads();
    }
    if (tid == 0) PART[blockIdx.x] = red[0];
}

__global__ __launch_bounds__(64) void final2(const float* __restrict__ PART,
                                             float* __restrict__ out)
{
    int tid = threadIdx.x;
    float s = (tid < 32) ? PART[tid] : 0.f;
    for (int o = 16; o > 0; o >>= 1) s += __shfl_down(s, o);
    if (tid == 0) out[0] = s * (1.f / 8192.f);
}

// ---------------------------------------------------------------------------
extern "C" void kernel_launch(void* const* d_in, const int* in_sizes, int n_in,
                              void* d_out, int out_size, void* d_ws, size_t ws_size,
                              hipStream_t stream)
{
    (void)in_sizes; (void)n_in; (void)out_size; (void)ws_size;
    const float* z    = (const float*)d_in[0];
    const float* eta  = (const float*)d_in[1];
    const float* dat  = (const float*)d_in[2];
    const float* Win  = (const float*)d_in[3];
    const float* bin  = (const float*)d_in[4];
    const float* Wctx = (const float*)d_in[5];
    const float* bctx = (const float*)d_in[6];
    const float* Wblk = (const float*)d_in[7];
    const float* bblk = (const float*)d_in[8];
    const float* Wout = (const float*)d_in[9];
    const float* bout = (const float*)d_in[10];
    float* out = (float*)d_out;

    char* w = (char*)d_ws;
    size_t off = 0;
    auto alloc = [&](size_t bytes) {
        void* p = w + off;
        off += (bytes + 255) & ~(size_t)255;
        return p;
    };
    u16*   W1  = (u16*)  alloc(8L * 256 * 96 * 2);
    float* B1  = (float*)alloc(8L * 256 * 4);
    u16*   WB  = (u16*)  alloc(8L * 4 * 256 * 256 * 2);
    u16*   WO  = (u16*)  alloc(8L * 3072 * 256 * 2);
    float* BO  = (float*)alloc(8L * 3072 * 4);
    u16*   AXE = (u16*)  alloc(8192L * 96 * 2);
    float* XFa = (float*)alloc(8192L * 64 * 4);
    float* XFb = (float*)alloc(8192L * 64 * 4);
    float* XC  = (float*)alloc(8192L * 64 * 4);
    u16*   HB  = (u16*)  alloc(8192L * 256 * 2);
    float* LDP = (float*)alloc(8192L * 32 * 4);
    float* DM  = (float*)alloc(66 * 4);
    float* PART= (float*)alloc(64 * 4);

    setup_w<<<dim3(2048), dim3(256), 0, stream>>>(
        Win, bin, Wctx, bctx, Wblk, Wout, bout, eta, W1, B1, WB, WO, BO, AXE);
    dstat<<<dim3(1), dim3(128), 0, stream>>>(dat, DM);
    prep0<<<dim3(2048), dim3(256), 0, stream>>>(z, XFa, AXE);

    for (int l = 0; l < 8; ++l) {
        float* XFin  = (l & 1) ? XFb : XFa;
        float* XFout = (l & 1) ? XFa : XFb;
        fused_mid<<<dim3(256), dim3(512), 0, stream>>>(
            AXE, W1 + (size_t)l * 256 * 96, B1 + l * 256,
            WB + (size_t)l * 4 * 65536, bblk + (size_t)l * 4 * 256, HB);
        gemm_out_spline<<<dim3(64, 32), dim3(256), 0, stream>>>(
            HB, WO + (size_t)l * 3072 * 256, BO + l * 3072, XFin,
            XC, XFout, AXE, LDP, (l == 0) ? 1 : 0);
    }
    final1<<<dim3(32), dim3(256), 0, stream>>>(XC, z, LDP, DM, PART);
    final2<<<dim3(1), dim3(64), 0, stream>>>(PART, out);
}